// Round 5
// baseline (6945.978 us; speedup 1.0000x reference)
//
#include <hip/hip_runtime.h>

typedef _Float16 f16;
typedef _Float16 f16x8 __attribute__((ext_vector_type(8)));
typedef float f32x4 __attribute__((ext_vector_type(4)));
typedef unsigned int u32;
typedef u32 u32x4 __attribute__((ext_vector_type(4)));

// Problem constants: N=64, T=1024, D=512, H=512, 4H=2048, K_cat=1024
//
// ws layout (bytes):
//   x_h    : fp16 x, [64][1024][512]            = 67,108,864 @ 0
//   Wcat   : fp16 [q=2048][k=1024] (q = u*4+g)  =  4,194,304 @ 67,108,864
//   b_p    : fp32 [2048] permuted               =      8,192 @ 71,303,168
//   h32    : u32  [2][64][512] tagged ping-pong = (tag<<16)|fp16(h)
//                                               =    262,144 @ 71,311,360
//   xw     : u32  [8 slots][64][2048] tagged xw FIFO = (tt+1)<<16|fp16(xw)
//                                               =  4,194,304 @ 71,573,504
//   prog   : u32  [256] consumer progress       =      1,024 @ 75,767,808
#define OFF_WCAT  67108864L
#define OFF_BP    71303168L
#define OFF_H32   71311360L
#define OFF_XW    71573504L
#define OFF_PROG  75767808L

constexpr int AS = 536;                 // LDS row stride in halves
constexpr int XW_DEPTH = 8;             // xw FIFO slots (power of 2)

__global__ void prep_kernel(const float* __restrict__ x, const float* __restrict__ h0,
                            const float* __restrict__ Wx, const float* __restrict__ Wh,
                            const float* __restrict__ b,
                            f16* __restrict__ x_h, f16* __restrict__ Wcat,
                            float* __restrict__ b_p, u32* __restrict__ h32,
                            u32* __restrict__ xw, u32* __restrict__ prog)
{
    const int tid = blockIdx.x * blockDim.x + threadIdx.x;   // 4,194,304 threads
    if (tid < 4194304) {                                     // x -> fp16, 8/thread
        const float4* src = (const float4*)x;
        float4 a = src[2*tid], c = src[2*tid + 1];
        f16x8 v;
        v[0]=(f16)a.x; v[1]=(f16)a.y; v[2]=(f16)a.z; v[3]=(f16)a.w;
        v[4]=(f16)c.x; v[5]=(f16)c.y; v[6]=(f16)c.z; v[7]=(f16)c.w;
        *(f16x8*)(x_h + (long)tid*8) = v;
    }
    // Wcat[q][k]: q = u*4 + g;  k<512 -> Wx[k][g*512+u], k>=512 -> Wh[k-512][g*512+u]
    if (tid < 2097152) {
        int q = tid >> 10, k = tid & 1023;
        int u = q >> 2, g = q & 3;
        float v = (k < 512) ? Wx[(long)k*2048 + g*512 + u]
                            : Wh[(long)(k-512)*2048 + g*512 + u];
        Wcat[tid] = (f16)v;
    }
    if (tid < 32768) {
        union { f16 h; unsigned short s; } cv; cv.h = (f16)h0[tid];
        h32[tid]         = (u32)cv.s;        // buffer 0: tag 0 | h0
        h32[32768 + tid] = 0xFFFF0000u;      // buffer 1: invalid tag
    }
    if (tid < 1048576) xw[tid] = 0u;         // FIFO tags: 0 never matches tt+1
    if (tid < 2048)  b_p[tid] = b[(tid & 3)*512 + (tid >> 2)];
    if (tid < 256)   prog[tid] = 0u;
}

// ---- coherent memory helpers (LLC path, sc0 sc1 — proven rounds 0/2/4) -----
// "=&v" early-clobber everywhere: outputs must never alias the 64-bit address
// pairs (a clobbered address inside a poll loop faults the GPU).

__device__ __forceinline__ void ld16_coh(const u32* p, u32x4& a, u32x4& b,
                                         u32x4& c, u32x4& d)
{
    asm volatile("global_load_dwordx4 %0, %4, off sc0 sc1\n\t"
                 "global_load_dwordx4 %1, %5, off sc0 sc1\n\t"
                 "global_load_dwordx4 %2, %6, off sc0 sc1\n\t"
                 "global_load_dwordx4 %3, %7, off sc0 sc1\n\t"
                 "s_waitcnt vmcnt(0)"
                 : "=&v"(a), "=&v"(b), "=&v"(c), "=&v"(d)
                 : "v"(p), "v"(p + 4), "v"(p + 8), "v"(p + 12)
                 : "memory");
}

__device__ __forceinline__ unsigned ld_flag(const unsigned int* p)
{
    unsigned v;
    asm volatile("global_load_dword %0, %1, off sc0 sc1\n\ts_waitcnt vmcnt(0)"
                 : "=&v"(v) : "v"(p) : "memory");
    return v;
}

__device__ __forceinline__ void st_w32(u32* p, unsigned v)
{
    asm volatile("global_store_dword %0, %1, off sc0 sc1" :: "v"(p), "v"(v) : "memory");
}

// issue-only load (no waitcnt): T14 early-issue; waited later via "+v" pairing
__device__ __forceinline__ void ld4_nw(const u32* p, u32x4& v)
{
    asm volatile("global_load_dwordx4 %0, %1, off sc0 sc1"
                 : "=&v"(v) : "v"(p) : "memory");
}

__device__ __forceinline__ float pay(u32 w)     // low-16 fp16 payload -> f32
{
    union { unsigned short s; f16 h; } u; u.s = (unsigned short)w;
    return (float)u.h;
}

// Poll this thread's 16 tagged h-words until all tags == tgt, then pack the
// fp16 payloads into the LDS Ah tile (proven round 4).
__device__ __forceinline__ void poll_stage(f16* __restrict__ Ah,
                                           const u32* __restrict__ wbase,
                                           unsigned tgt, int tid)
{
    const u32* p = wbase + tid * 16;
    u32x4 A, B, C, D;
    while (true) {
        ld16_coh(p, A, B, C, D);
        unsigned m;
        m  = (A.x>>16)^tgt; m |= (A.y>>16)^tgt; m |= (A.z>>16)^tgt; m |= (A.w>>16)^tgt;
        m |= (B.x>>16)^tgt; m |= (B.y>>16)^tgt; m |= (B.z>>16)^tgt; m |= (B.w>>16)^tgt;
        m |= (C.x>>16)^tgt; m |= (C.y>>16)^tgt; m |= (C.z>>16)^tgt; m |= (C.w>>16)^tgt;
        m |= (D.x>>16)^tgt; m |= (D.y>>16)^tgt; m |= (D.z>>16)^tgt; m |= (D.w>>16)^tgt;
        if (m == 0) break;
    }
    u32x4 lo, hi;
    lo.x = (A.x & 0xFFFFu) | (A.y << 16); lo.y = (A.z & 0xFFFFu) | (A.w << 16);
    lo.z = (B.x & 0xFFFFu) | (B.y << 16); lo.w = (B.z & 0xFFFFu) | (B.w << 16);
    hi.x = (C.x & 0xFFFFu) | (C.y << 16); hi.y = (C.z & 0xFFFFu) | (C.w << 16);
    hi.z = (D.x & 0xFFFFu) | (D.y << 16); hi.w = (D.z & 0xFFFFu) | (D.w << 16);
    const int row = tid >> 5;
    const int col = (tid & 31) * 16;
    u32* dst = (u32*)(Ah + row * AS + col);
    *(u32x4*)dst       = lo;
    *(u32x4*)(dst + 4) = hi;
}

// K=512 of one 16x16 tile: 16 MFMAs, 4 independent partial-sum chains.
__device__ __forceinline__ void mfma_quad(const f16* A, int aoff, const f16x8* wf,
                                          f32x4& a0, f32x4& a1, f32x4& a2, f32x4& a3)
{
    #pragma unroll
    for (int kk = 0; kk < 16; kk += 4) {
        f16x8 f0 = *(const f16x8*)(A + aoff + (kk+0) * 32);
        f16x8 f1 = *(const f16x8*)(A + aoff + (kk+1) * 32);
        f16x8 f2 = *(const f16x8*)(A + aoff + (kk+2) * 32);
        f16x8 f3 = *(const f16x8*)(A + aoff + (kk+3) * 32);
        a0 = __builtin_amdgcn_mfma_f32_16x16x32_f16(f0, wf[kk+0], a0, 0, 0, 0);
        a1 = __builtin_amdgcn_mfma_f32_16x16x32_f16(f1, wf[kk+1], a1, 0, 0, 0);
        a2 = __builtin_amdgcn_mfma_f32_16x16x32_f16(f2, wf[kk+2], a2, 0, 0, 0);
        a3 = __builtin_amdgcn_mfma_f32_16x16x32_f16(f3, wf[kk+3], a3, 0, 0, 0);
    }
}

// LDS-counter barrier among the 4 recurrence waves ONLY (producer waves of the
// block never participate — s_barrier is unusable with mixed wave roles).
__device__ __forceinline__ void cbar(unsigned* cnt, unsigned& phase)
{
    phase += 4;
    asm volatile("s_waitcnt lgkmcnt(0)" ::: "memory");   // my LDS writes committed
    if ((threadIdx.x & 63) == 0) atomicAdd(cnt, 1u);
    while (*((volatile unsigned*)cnt) < phase) {}
    asm volatile("" ::: "memory");
}

// Persistent kernel. 256 blocks x 512 threads.
// Waves 0-3 (tid<256): recurrence consumer — group g = blk%8, wgl = blk/8.
//   Per step: 16 h-MFMA -> epilogue (+ tag-checked prefetched xw) -> h32 store
//   -> cbar -> progress store -> poll h32 -> pack Ah -> cbar.
// Waves 4-7: xw producer — 1024 waves, tile w&511 (4 row-slabs x 128 col-tiles,
//   full M=16), parity w>>9. Runs up to XW_DEPTH ahead; tagged words make the
//   data self-certifying; consumers' progress counters gate slot reuse.
//   Grounded chain (tt<XW_DEPTH unconditional) => deadlock-free.
__global__ __launch_bounds__(512, 1) void lstm_kernel(
    const f16* __restrict__ x_h, const f16* __restrict__ Wcat,
    const float* __restrict__ b_p, u32* __restrict__ h32,
    u32* __restrict__ xw, u32* __restrict__ prog, float* __restrict__ out)
{
    __shared__ f16 Ah[8 * AS];
    __shared__ float epil[4 * 16 * 20];
    __shared__ unsigned rcnt;

    const int blk  = blockIdx.x;
    const int tid  = threadIdx.x;
    const int lane = tid & 63;
    const int c    = lane & 15;
    const int kg   = lane >> 4;
    const int rb   = kg;

    if (tid == 0) rcnt = 0u;
    __syncthreads();                        // once, all 8 waves — then roles split

    if (tid < 256) {
        // ---------------- recurrence consumer ----------------
        const int g = blk & 7, wgl = blk >> 3, n0 = g * 8;
        const int wave = tid >> 6;
        const int ub = wgl * 16 + wave * 4, q0 = ub * 4;

        f16x8 wfh[16];                       // h-part weights resident
        {
            const f16* wp = Wcat + (long)(q0 + c) * 1024 + 512 + kg * 8;
            #pragma unroll
            for (int kk = 0; kk < 16; ++kk) wfh[kk] = *(const f16x8*)(wp + kk * 32);
        }
        const int aoff = (lane & 7) * AS + kg * 8;
        float* ep = epil + wave * 320;
        const int er = lane >> 2, eu = lane & 3;
        const float4 b4 = *(const float4*)(b_p + q0 + eu * 4);   // per-cell biases
        float cst = 0.f;

        u32* hb0 = h32 + n0 * 512;
        u32* hb1 = h32 + 32768 + n0 * 512;
        u32* mypr = prog + g * 32 + wgl;
        const long xwrow = (long)(n0 + er) * 2048 + q0 + eu * 4; // cell's 4 gates

        // prologue: prefetch xw(t=0), stage h0
        u32x4 wpre;
        if (lane < 32) ld4_nw(xw + xwrow, wpre);
        poll_stage(Ah, hb0, 0u, tid);
        unsigned phase = 0;
        cbar(&rcnt, phase);

        for (int t = 0; t < 1024; ++t) {
            f32x4 a0 = {0.f,0.f,0.f,0.f}, a1 = {0.f,0.f,0.f,0.f};
            f32x4 a2 = {0.f,0.f,0.f,0.f}, a3 = {0.f,0.f,0.f,0.f};
            mfma_quad(Ah, aoff, wfh, a0, a1, a2, a3);            // h part only

            #pragma unroll
            for (int j = 0; j < 4; ++j)
                ep[(rb * 4 + j) * 20 + c] = (a0[j] + a1[j]) + (a2[j] + a3[j]);

            if (lane < 32) {
                float4 g4 = *(const float4*)(ep + er * 20 + eu * 4);
                // xw: wait prefetched regs, verify tags (slot ready ~7 steps early)
                u32x4 w = wpre;
                asm volatile("s_waitcnt vmcnt(0)" : "+v"(w) :: "memory");
                __builtin_amdgcn_sched_barrier(0);
                const unsigned want = (unsigned)(t + 1);
                const u32* xwp = xw + (long)(t & (XW_DEPTH-1)) * 131072 + xwrow;
                while ((w.x >> 16) != want || (w.y >> 16) != want ||
                       (w.z >> 16) != want || (w.w >> 16) != want) {
                    asm volatile("global_load_dwordx4 %0, %1, off sc0 sc1\n\t"
                                 "s_waitcnt vmcnt(0)"
                                 : "=&v"(w) : "v"(xwp) : "memory");
                }
                g4.x += b4.x + pay(w.x);
                g4.y += b4.y + pay(w.y);
                g4.z += b4.z + pay(w.z);
                g4.w += b4.w + pay(w.w);
                float iv = 1.f / (1.f + __expf(-g4.x));
                float fv = 1.f / (1.f + __expf(-g4.y));
                float ov = 1.f / (1.f + __expf(-g4.z));
                float gv = 2.f / (1.f + __expf(-2.f * g4.w)) - 1.f;   // tanh
                float cn = fv * cst + iv * gv;
                cst = cn;
                float th = 2.f / (1.f + __expf(-2.f * cn)) - 1.f;     // tanh
                float hval = ov * th;
                const int n = n0 + er;
                const int u = ub + eu;
                out[((long)n * 1024 + t) * 512 + u] = hval;
                if (t < 1023) {
                    union { f16 h; unsigned short s; } cv; cv.h = (f16)hval;
                    unsigned hw = ((unsigned)(t + 1) << 16) | (unsigned)cv.s;
                    st_w32((((t + 1) & 1) ? hb1 : hb0) + er * 512 + u, hw);
                }
            }

            cbar(&rcnt, phase);              // all waves done reading Ah / xw[t]
            if (tid == 0) st_w32(mypr, (unsigned)(t + 1));   // xw[t] consumed

            if (t < 1023) {
                if (lane < 32)               // prefetch next xw (speculative)
                    ld4_nw(xw + (long)((t + 1) & (XW_DEPTH-1)) * 131072 + xwrow, wpre);
                poll_stage(Ah, ((t + 1) & 1) ? hb1 : hb0, (unsigned)(t + 1), tid);
                cbar(&rcnt, phase);          // Ah(t+1) packed
            }
        }
    } else {
        // ---------------- xw producer ----------------
        const int w    = blk * 4 + (tid >> 6) - 4;   // 0..1023
        const int tile = w & 511;
        const int par  = w >> 9;                     // parity 0/1
        const int slab = tile >> 7;                  // 4 row-slabs of 16
        const int q0p  = (tile & 127) * 16;          // col tile

        f16x8 wfx[16];                               // x-part weights resident
        {
            const f16* wp = Wcat + (long)(q0p + c) * 1024 + kg * 8;
            #pragma unroll
            for (int kk = 0; kk < 16; ++kk) wfx[kk] = *(const f16x8*)(wp + kk * 32);
        }
        // A-frag: row = lane&15 (= c), k-chunk = kg*8 (+ kk*32)
        const f16* xa = x_h + ((long)(slab * 16 + c) * 1024) * 512 + kg * 8;
        const u32* prp = prog + slab * 64 + lane;    // this slab's 64 consumer WGs

        for (int tt = par; tt < 1024; tt += 2) {
            if (tt >= XW_DEPTH) {                    // gate slot reuse on consumers
                while (true) {
                    unsigned pr = ld_flag(prp);
                    if (__all((int)pr >= tt - (XW_DEPTH - 1))) break;
                    __builtin_amdgcn_s_sleep(8);
                }
            }
            const f16* at = xa + (long)tt * 512;
            f16x8 af[16];
            #pragma unroll
            for (int kk = 0; kk < 16; ++kk) af[kk] = *(const f16x8*)(at + kk * 32);
            f32x4 a0 = {0.f,0.f,0.f,0.f}, a1 = {0.f,0.f,0.f,0.f};
            f32x4 a2 = {0.f,0.f,0.f,0.f}, a3 = {0.f,0.f,0.f,0.f};
            #pragma unroll
            for (int kk = 0; kk < 16; kk += 4) {
                a0 = __builtin_amdgcn_mfma_f32_16x16x32_f16(af[kk+0], wfx[kk+0], a0, 0, 0, 0);
                a1 = __builtin_amdgcn_mfma_f32_16x16x32_f16(af[kk+1], wfx[kk+1], a1, 0, 0, 0);
                a2 = __builtin_amdgcn_mfma_f32_16x16x32_f16(af[kk+2], wfx[kk+2], a2, 0, 0, 0);
                a3 = __builtin_amdgcn_mfma_f32_16x16x32_f16(af[kk+3], wfx[kk+3], a3, 0, 0, 0);
            }
            const unsigned tagw = (unsigned)(tt + 1) << 16;
            u32* d = xw + (long)(tt & (XW_DEPTH-1)) * 131072
                        + (long)(slab * 16 + rb * 4) * 2048 + q0p + c;
            #pragma unroll
            for (int j = 0; j < 4; ++j) {
                float v = (a0[j] + a1[j]) + (a2[j] + a3[j]);
                union { f16 h; unsigned short s; } cv; cv.h = (f16)v;
                st_w32(d + (long)j * 2048, tagw | (unsigned)cv.s);
            }
        }
    }
}

extern "C" void kernel_launch(void* const* d_in, const int* in_sizes, int n_in,
                              void* d_out, int out_size, void* d_ws, size_t ws_size,
                              hipStream_t stream)
{
    const float* x  = (const float*)d_in[0];
    const float* h0 = (const float*)d_in[1];
    const float* Wx = (const float*)d_in[2];
    const float* Wh = (const float*)d_in[3];
    const float* b  = (const float*)d_in[4];
    float* out = (float*)d_out;

    char* ws = (char*)d_ws;
    f16*   x_h  = (f16*)(ws);
    f16*   Wcat = (f16*)(ws + OFF_WCAT);
    float* b_p  = (float*)(ws + OFF_BP);
    u32*   h32  = (u32*)(ws + OFF_H32);
    u32*   xw   = (u32*)(ws + OFF_XW);
    u32*   prog = (u32*)(ws + OFF_PROG);

    prep_kernel<<<16384, 256, 0, stream>>>(x, h0, Wx, Wh, b, x_h, Wcat, b_p, h32, xw, prog);
    lstm_kernel<<<256, 512, 0, stream>>>(x_h, Wcat, b_p, h32, xw, prog, out);
}

// Round 6
// 3726.994 us; speedup vs baseline: 1.8637x; 1.8637x over previous
//
#include <hip/hip_runtime.h>

typedef _Float16 f16;
typedef _Float16 f16x8 __attribute__((ext_vector_type(8)));
typedef float f32x4 __attribute__((ext_vector_type(4)));
typedef unsigned int u32;
typedef u32 u32x4 __attribute__((ext_vector_type(4)));

// Problem constants: N=64, T=1024, D=512, H=512, 4H=2048, K_cat=1024
//
// ws layout (bytes):
//   x_h    : fp16 x, [64][1024][512]            = 67,108,864 @ 0
//   Wcat   : fp16 [q=2048][k=1024] (q = u*4+g)  =  4,194,304 @ 67,108,864
//   b_p    : fp32 [2048] permuted               =      8,192 @ 71,303,168
//   h32    : u32  [2][64][512] tagged ping-pong = (tag<<16)|fp16(h)
//                                               =    262,144 @ 71,311,360
#define OFF_WCAT  67108864L
#define OFF_BP    71303168L
#define OFF_H32   71311360L

constexpr int AS = 536;                 // LDS row stride in halves

__global__ void prep_kernel(const float* __restrict__ x, const float* __restrict__ h0,
                            const float* __restrict__ Wx, const float* __restrict__ Wh,
                            const float* __restrict__ b,
                            f16* __restrict__ x_h, f16* __restrict__ Wcat,
                            float* __restrict__ b_p, u32* __restrict__ h32)
{
    const int tid = blockIdx.x * blockDim.x + threadIdx.x;   // 4,194,304 threads
    if (tid < 4194304) {                                     // x -> fp16, 8/thread
        const float4* src = (const float4*)x;
        float4 a = src[2*tid], c = src[2*tid + 1];
        f16x8 v;
        v[0]=(f16)a.x; v[1]=(f16)a.y; v[2]=(f16)a.z; v[3]=(f16)a.w;
        v[4]=(f16)c.x; v[5]=(f16)c.y; v[6]=(f16)c.z; v[7]=(f16)c.w;
        *(f16x8*)(x_h + (long)tid*8) = v;
    }
    // Wcat[q][k]: q = u*4 + g;  k<512 -> Wx[k][g*512+u], k>=512 -> Wh[k-512][g*512+u]
    if (tid < 2097152) {
        int q = tid >> 10, k = tid & 1023;
        int u = q >> 2, g = q & 3;
        float v = (k < 512) ? Wx[(long)k*2048 + g*512 + u]
                            : Wh[(long)(k-512)*2048 + g*512 + u];
        Wcat[tid] = (f16)v;
    }
    if (tid < 32768) {
        union { f16 h; unsigned short s; } cv; cv.h = (f16)h0[tid];
        h32[tid]         = (u32)cv.s;        // buffer 0: tag 0 | h0
        h32[32768 + tid] = 0xFFFF0000u;      // buffer 1: invalid tag
    }
    if (tid < 2048)  b_p[tid] = b[(tid & 3)*512 + (tid >> 2)];
}

// ---- coherent memory helpers (LLC path, sc0 sc1 — proven rounds 0/2/4) -----
// "=&v" early-clobber everywhere: outputs must never alias the 64-bit address
// pairs (a clobbered address inside a poll loop faults the GPU).

__device__ __forceinline__ void ld16_coh(const u32* p, u32x4& a, u32x4& b,
                                         u32x4& c, u32x4& d)
{
    asm volatile("global_load_dwordx4 %0, %4, off sc0 sc1\n\t"
                 "global_load_dwordx4 %1, %5, off sc0 sc1\n\t"
                 "global_load_dwordx4 %2, %6, off sc0 sc1\n\t"
                 "global_load_dwordx4 %3, %7, off sc0 sc1\n\t"
                 "s_waitcnt vmcnt(0)"
                 : "=&v"(a), "=&v"(b), "=&v"(c), "=&v"(d)
                 : "v"(p), "v"(p + 4), "v"(p + 8), "v"(p + 12)
                 : "memory");
}

__device__ __forceinline__ void st_w32(u32* p, unsigned v)
{
    asm volatile("global_store_dword %0, %1, off sc0 sc1" :: "v"(p), "v"(v) : "memory");
}

// Poll this thread's 16 tagged h-words until all tags == tgt, then pack the
// fp16 payloads into the given LDS Ah tile (proven round 4).
__device__ __forceinline__ void poll_stage(f16* __restrict__ Ah,
                                           const u32* __restrict__ wbase,
                                           unsigned tgt, int tid)
{
    const u32* p = wbase + tid * 16;
    u32x4 A, B, C, D;
    while (true) {
        ld16_coh(p, A, B, C, D);
        unsigned m;
        m  = (A.x>>16)^tgt; m |= (A.y>>16)^tgt; m |= (A.z>>16)^tgt; m |= (A.w>>16)^tgt;
        m |= (B.x>>16)^tgt; m |= (B.y>>16)^tgt; m |= (B.z>>16)^tgt; m |= (B.w>>16)^tgt;
        m |= (C.x>>16)^tgt; m |= (C.y>>16)^tgt; m |= (C.z>>16)^tgt; m |= (C.w>>16)^tgt;
        m |= (D.x>>16)^tgt; m |= (D.y>>16)^tgt; m |= (D.z>>16)^tgt; m |= (D.w>>16)^tgt;
        if (m == 0) break;
    }
    u32x4 lo, hi;
    lo.x = (A.x & 0xFFFFu) | (A.y << 16); lo.y = (A.z & 0xFFFFu) | (A.w << 16);
    lo.z = (B.x & 0xFFFFu) | (B.y << 16); lo.w = (B.z & 0xFFFFu) | (B.w << 16);
    hi.x = (C.x & 0xFFFFu) | (C.y << 16); hi.y = (C.z & 0xFFFFu) | (C.w << 16);
    hi.z = (D.x & 0xFFFFu) | (D.y << 16); hi.w = (D.z & 0xFFFFu) | (D.w << 16);
    const int row = tid >> 5;
    const int col = (tid & 31) * 16;
    u32* dst = (u32*)(Ah + row * AS + col);
    *(u32x4*)dst       = lo;
    *(u32x4*)(dst + 4) = hi;
}

// K=512 of one 16x16 tile from LDS: 16 MFMAs, 4 independent partial-sum chains.
__device__ __forceinline__ void mfma_quad(const f16* A, int aoff, const f16x8* wf,
                                          f32x4& a0, f32x4& a1, f32x4& a2, f32x4& a3)
{
    #pragma unroll
    for (int kk = 0; kk < 16; kk += 4) {
        f16x8 f0 = *(const f16x8*)(A + aoff + (kk+0) * 32);
        f16x8 f1 = *(const f16x8*)(A + aoff + (kk+1) * 32);
        f16x8 f2 = *(const f16x8*)(A + aoff + (kk+2) * 32);
        f16x8 f3 = *(const f16x8*)(A + aoff + (kk+3) * 32);
        a0 = __builtin_amdgcn_mfma_f32_16x16x32_f16(f0, wf[kk+0], a0, 0, 0, 0);
        a1 = __builtin_amdgcn_mfma_f32_16x16x32_f16(f1, wf[kk+1], a1, 0, 0, 0);
        a2 = __builtin_amdgcn_mfma_f32_16x16x32_f16(f2, wf[kk+2], a2, 0, 0, 0);
        a3 = __builtin_amdgcn_mfma_f32_16x16x32_f16(f3, wf[kk+3], a3, 0, 0, 0);
    }
}

// K=512 from per-lane registers (x A-fragments live in VGPRs, no LDS).
__device__ __forceinline__ void mfma_quad_reg(const f16x8* xf, const f16x8* wf,
                                              f32x4& a0, f32x4& a1, f32x4& a2, f32x4& a3)
{
    #pragma unroll
    for (int kk = 0; kk < 16; kk += 4) {
        a0 = __builtin_amdgcn_mfma_f32_16x16x32_f16(xf[kk+0], wf[kk+0], a0, 0, 0, 0);
        a1 = __builtin_amdgcn_mfma_f32_16x16x32_f16(xf[kk+1], wf[kk+1], a1, 0, 0, 0);
        a2 = __builtin_amdgcn_mfma_f32_16x16x32_f16(xf[kk+2], wf[kk+2], a2, 0, 0, 0);
        a3 = __builtin_amdgcn_mfma_f32_16x16x32_f16(xf[kk+3], wf[kk+3], a3, 0, 0, 0);
    }
}

// LDS-only workgroup barrier: orders ds ops; leaves global stores/loads in flight.
__device__ __forceinline__ void bar_lds()
{
    asm volatile("s_waitcnt lgkmcnt(0)" ::: "memory");
    __builtin_amdgcn_s_barrier();
}

// One recurrence step. Parity-static args: AH_R = LDS tile holding h_T (read);
// AH_P = other tile (pack h_{T+1}); HB_N = h32 buffer for h_{T+1}; XN = regs
// holding x_{T+1} fragments; XR = reg set to refill with x_{T+2}.
// acc (a0..a3) enters holding the x-part of step T; leaves holding x-part T+1.
#define LSTM_STEP(T, AH_R, AH_P, HB_N, XN, XR)                                \
  {                                                                           \
    mfma_quad(AH_R, aoff, wfh, a0, a1, a2, a3);        /* += h_T @ Wh */      \
    _Pragma("unroll")                                                         \
    for (int j = 0; j < 4; ++j)                                               \
        ep[(rb * 4 + j) * 20 + c] = (a0[j] + a1[j]) + (a2[j] + a3[j]);        \
    if (lane < 32) {                                                          \
        float4 g4 = *(const float4*)(ep + er * 20 + eu * 4);   /* i,f,o,g */  \
        g4.x += b4.x; g4.y += b4.y; g4.z += b4.z; g4.w += b4.w;               \
        float iv = 1.f / (1.f + __expf(-g4.x));                               \
        float fv = 1.f / (1.f + __expf(-g4.y));                               \
        float ov = 1.f / (1.f + __expf(-g4.z));                               \
        float gv = 2.f / (1.f + __expf(-2.f * g4.w)) - 1.f;    /* tanh */     \
        float cn = fv * cst + iv * gv;                                        \
        cst = cn;                                                             \
        float th = 2.f / (1.f + __expf(-2.f * cn)) - 1.f;      /* tanh */     \
        float hval = ov * th;                                                 \
        out[((long)(n0 + er) * 1024 + (T)) * 512 + ub + eu] = hval;           \
        if ((T) < 1023) {                                                     \
            union { f16 h; unsigned short s; } cv; cv.h = (f16)hval;          \
            unsigned hw = ((unsigned)((T) + 1) << 16) | (unsigned)cv.s;       \
            st_w32((HB_N) + er * 512 + ub + eu, hw);   /* fire & forget */    \
        }                                                                     \
    }                                                                         \
    if ((T) < 1023) {                                                         \
        a0 = (f32x4){0.f,0.f,0.f,0.f}; a1 = (f32x4){0.f,0.f,0.f,0.f};         \
        a2 = (f32x4){0.f,0.f,0.f,0.f}; a3 = (f32x4){0.f,0.f,0.f,0.f};         \
        mfma_quad_reg(XN, wfx, a0, a1, a2, a3);        /* x-part of T+1 */    \
        if ((T) < 1022) {                                                     \
            _Pragma("unroll")                                                 \
            for (int kk = 0; kk < 16; ++kk)                                   \
                XR[kk] = *(const f16x8*)(xlb + (long)((T) + 2) * 512 + kk*32);\
        }                                                                     \
        poll_stage(AH_P, HB_N, (unsigned)((T) + 1), tid);                     \
        bar_lds();                                     /* AH_P packed by all */\
    }                                                                         \
  }

// Persistent recurrence kernel. 256 blocks x 256 threads (proven round-4 shape).
// group g = blk%8, wgl = blk/8 in [0,32). Group owns batch rows [8g,8g+8).
// Wave owns 4 hidden units -> 16 gate columns = one 16x16 MFMA N-tile, K=1024.
// x A-fragments live in per-lane registers (double-buffered, prefetched one
// step ahead from L1/L2) — no Ax LDS tile, ONE barrier per step.
__global__ __launch_bounds__(256, 1) void lstm_kernel(
    const f16* __restrict__ x_h, const f16* __restrict__ Wcat,
    const float* __restrict__ b_p, u32* __restrict__ h32,
    float* __restrict__ out)
{
    __shared__ f16 Ah0[8 * AS];
    __shared__ f16 Ah1[8 * AS];
    __shared__ float epil[4 * 16 * 20];     // per-wave 16x20 gate transpose scratch

    const int blk  = blockIdx.x;
    const int g    = blk & 7;
    const int wgl  = blk >> 3;
    const int n0   = g * 8;
    const int tid  = threadIdx.x;
    const int wave = tid >> 6;
    const int lane = tid & 63;
    const int c    = lane & 15;             // tile column
    const int kg   = lane >> 4;             // k-group 0..3
    const int rb   = kg;
    const int ub   = wgl * 16 + wave * 4;   // first hidden unit of this wave
    const int q0   = ub * 4;                // first gate column

    // Weight B-fragments: x-part and h-part (compiler may cache or re-load; L1-hot).
    f16x8 wfx[16], wfh[16];
    {
        const f16* wp = Wcat + (long)(q0 + c) * 1024 + kg * 8;
        #pragma unroll
        for (int kk = 0; kk < 16; ++kk) wfx[kk] = *(const f16x8*)(wp + kk * 32);
        #pragma unroll
        for (int kk = 0; kk < 16; ++kk) wfh[kk] = *(const f16x8*)(wp + 512 + kk * 32);
    }

    const int aoff = (lane & 7) * AS + kg * 8;
    float* ep = epil + wave * 320;
    const int er = lane >> 2;               // batch row 0..7 (epilogue)
    const int eu = lane & 3;                // unit-local 0..3
    const float4 b4 = *(const float4*)(b_p + q0 + eu * 4);   // per-cell biases
    float cst = 0.f;

    u32* hb0 = h32 + n0 * 512;
    u32* hb1 = h32 + 32768 + n0 * 512;

    // per-lane x A-fragment base: row = lane&7, k-chunk = kg*8 (+ kk*32)
    const f16* xlb = x_h + ((long)(n0 + (lane & 7)) * 1024) * 512 + kg * 8;

    // ---- prologue: x_0, x_1 frags to regs; x-part of t=0; stage h_0 ----
    f16x8 xA[16], xB[16];
    #pragma unroll
    for (int kk = 0; kk < 16; ++kk) xA[kk] = *(const f16x8*)(xlb + kk * 32);
    #pragma unroll
    for (int kk = 0; kk < 16; ++kk) xB[kk] = *(const f16x8*)(xlb + 512 + kk * 32);

    f32x4 a0 = {0.f,0.f,0.f,0.f}, a1 = {0.f,0.f,0.f,0.f};
    f32x4 a2 = {0.f,0.f,0.f,0.f}, a3 = {0.f,0.f,0.f,0.f};
    mfma_quad_reg(xA, wfx, a0, a1, a2, a3);      // x part, t=0

    poll_stage(Ah0, hb0, 0u, tid);               // prep wrote tag 0
    bar_lds();

    for (int t = 0; t < 1024; t += 2) {
        LSTM_STEP(t,     Ah0, Ah1, hb1, xB, xA);   // h_t in Ah0; pack h_{t+1}->Ah1
        LSTM_STEP(t + 1, Ah1, Ah0, hb0, xA, xB);   // h_{t+1} in Ah1; pack ->Ah0
    }
}

extern "C" void kernel_launch(void* const* d_in, const int* in_sizes, int n_in,
                              void* d_out, int out_size, void* d_ws, size_t ws_size,
                              hipStream_t stream)
{
    const float* x  = (const float*)d_in[0];
    const float* h0 = (const float*)d_in[1];
    const float* Wx = (const float*)d_in[2];
    const float* Wh = (const float*)d_in[3];
    const float* b  = (const float*)d_in[4];
    float* out = (float*)d_out;

    char* ws = (char*)d_ws;
    f16*   x_h  = (f16*)(ws);
    f16*   Wcat = (f16*)(ws + OFF_WCAT);
    float* b_p  = (float*)(ws + OFF_BP);
    u32*   h32  = (u32*)(ws + OFF_H32);

    prep_kernel<<<16384, 256, 0, stream>>>(x, h0, Wx, Wh, b, x_h, Wcat, b_p, h32);
    lstm_kernel<<<256, 256, 0, stream>>>(x_h, Wcat, b_p, h32, out);
}

// Round 7
// 2491.648 us; speedup vs baseline: 2.7877x; 1.4958x over previous
//
#include <hip/hip_runtime.h>

typedef _Float16 f16;
typedef _Float16 f16x8 __attribute__((ext_vector_type(8)));
typedef float f32x4 __attribute__((ext_vector_type(4)));
typedef unsigned int u32;
typedef u32 u32x4 __attribute__((ext_vector_type(4)));

// Problem constants: N=64, T=1024, D=512, H=512, 4H=2048, K_cat=1024
//
// ws layout (bytes):
//   x_h    : fp16 x, [64][1024][512]            = 67,108,864 @ 0
//   Wcat   : fp16 [q=2048][k=1024] (q = u*4+g)  =  4,194,304 @ 67,108,864
//   b_p    : fp32 [2048] permuted               =      8,192 @ 71,303,168
//   h32    : u32  [2][64][512] tagged ping-pong = (tag<<16)|fp16(h)
//                                               =    262,144 @ 71,311,360
#define OFF_WCAT  67108864L
#define OFF_BP    71303168L
#define OFF_H32   71311360L

constexpr int AS = 536;                 // LDS row stride in halves

__global__ void prep_kernel(const float* __restrict__ x, const float* __restrict__ h0,
                            const float* __restrict__ Wx, const float* __restrict__ Wh,
                            const float* __restrict__ b,
                            f16* __restrict__ x_h, f16* __restrict__ Wcat,
                            float* __restrict__ b_p, u32* __restrict__ h32)
{
    const int tid = blockIdx.x * blockDim.x + threadIdx.x;   // 4,194,304 threads
    if (tid < 4194304) {                                     // x -> fp16, 8/thread
        const float4* src = (const float4*)x;
        float4 a = src[2*tid], c = src[2*tid + 1];
        f16x8 v;
        v[0]=(f16)a.x; v[1]=(f16)a.y; v[2]=(f16)a.z; v[3]=(f16)a.w;
        v[4]=(f16)c.x; v[5]=(f16)c.y; v[6]=(f16)c.z; v[7]=(f16)c.w;
        *(f16x8*)(x_h + (long)tid*8) = v;
    }
    // Wcat[q][k]: q = u*4 + g;  k<512 -> Wx[k][g*512+u], k>=512 -> Wh[k-512][g*512+u]
    if (tid < 2097152) {
        int q = tid >> 10, k = tid & 1023;
        int u = q >> 2, g = q & 3;
        float v = (k < 512) ? Wx[(long)k*2048 + g*512 + u]
                            : Wh[(long)(k-512)*2048 + g*512 + u];
        Wcat[tid] = (f16)v;
    }
    if (tid < 32768) {
        union { f16 h; unsigned short s; } cv; cv.h = (f16)h0[tid];
        h32[tid]         = (u32)cv.s;        // buffer 0: tag 0 | h0
        h32[32768 + tid] = 0xFFFF0000u;      // buffer 1: invalid tag
    }
    if (tid < 2048)  b_p[tid] = b[(tid & 3)*512 + (tid >> 2)];
}

// ---- coherent memory helpers (LLC path, sc0 sc1 — proven rounds 0/2/4) -----
// "=&v" early-clobber everywhere: outputs must never alias the 64-bit address
// pairs (a clobbered address inside a poll loop faults the GPU).

__device__ __forceinline__ void ld16_coh(const u32* p, u32x4& a, u32x4& b,
                                         u32x4& c, u32x4& d)
{
    asm volatile("global_load_dwordx4 %0, %4, off sc0 sc1\n\t"
                 "global_load_dwordx4 %1, %5, off sc0 sc1\n\t"
                 "global_load_dwordx4 %2, %6, off sc0 sc1\n\t"
                 "global_load_dwordx4 %3, %7, off sc0 sc1\n\t"
                 "s_waitcnt vmcnt(0)"
                 : "=&v"(a), "=&v"(b), "=&v"(c), "=&v"(d)
                 : "v"(p), "v"(p + 4), "v"(p + 8), "v"(p + 12)
                 : "memory");
}

__device__ __forceinline__ void st_w32(u32* p, unsigned v)
{
    asm volatile("global_store_dword %0, %1, off sc0 sc1" :: "v"(p), "v"(v) : "memory");
}

// Poll this thread's 16 tagged h-words until all tags == tgt, then pack the
// fp16 payloads into the given LDS Ah tile (proven round 4).
__device__ __forceinline__ void poll_stage(f16* __restrict__ Ah,
                                           const u32* __restrict__ wbase,
                                           unsigned tgt, int tid)
{
    const u32* p = wbase + tid * 16;
    u32x4 A, B, C, D;
    while (true) {
        ld16_coh(p, A, B, C, D);
        unsigned m;
        m  = (A.x>>16)^tgt; m |= (A.y>>16)^tgt; m |= (A.z>>16)^tgt; m |= (A.w>>16)^tgt;
        m |= (B.x>>16)^tgt; m |= (B.y>>16)^tgt; m |= (B.z>>16)^tgt; m |= (B.w>>16)^tgt;
        m |= (C.x>>16)^tgt; m |= (C.y>>16)^tgt; m |= (C.z>>16)^tgt; m |= (C.w>>16)^tgt;
        m |= (D.x>>16)^tgt; m |= (D.y>>16)^tgt; m |= (D.z>>16)^tgt; m |= (D.w>>16)^tgt;
        if (m == 0) break;
    }
    u32x4 lo, hi;
    lo.x = (A.x & 0xFFFFu) | (A.y << 16); lo.y = (A.z & 0xFFFFu) | (A.w << 16);
    lo.z = (B.x & 0xFFFFu) | (B.y << 16); lo.w = (B.z & 0xFFFFu) | (B.w << 16);
    hi.x = (C.x & 0xFFFFu) | (C.y << 16); hi.y = (C.z & 0xFFFFu) | (C.w << 16);
    hi.z = (D.x & 0xFFFFu) | (D.y << 16); hi.w = (D.z & 0xFFFFu) | (D.w << 16);
    const int row = tid >> 5;
    const int col = (tid & 31) * 16;
    u32* dst = (u32*)(Ah + row * AS + col);
    *(u32x4*)dst       = lo;
    *(u32x4*)(dst + 4) = hi;
}

// K=512 of one 16x16 tile from LDS: 16 MFMAs, 4 independent partial-sum chains.
__device__ __forceinline__ void mfma_quad(const f16* A, int aoff, const f16x8* wf,
                                          f32x4& a0, f32x4& a1, f32x4& a2, f32x4& a3)
{
    #pragma unroll
    for (int kk = 0; kk < 16; kk += 4) {
        f16x8 f0 = *(const f16x8*)(A + aoff + (kk+0) * 32);
        f16x8 f1 = *(const f16x8*)(A + aoff + (kk+1) * 32);
        f16x8 f2 = *(const f16x8*)(A + aoff + (kk+2) * 32);
        f16x8 f3 = *(const f16x8*)(A + aoff + (kk+3) * 32);
        a0 = __builtin_amdgcn_mfma_f32_16x16x32_f16(f0, wf[kk+0], a0, 0, 0, 0);
        a1 = __builtin_amdgcn_mfma_f32_16x16x32_f16(f1, wf[kk+1], a1, 0, 0, 0);
        a2 = __builtin_amdgcn_mfma_f32_16x16x32_f16(f2, wf[kk+2], a2, 0, 0, 0);
        a3 = __builtin_amdgcn_mfma_f32_16x16x32_f16(f3, wf[kk+3], a3, 0, 0, 0);
    }
}

// LDS-only workgroup barrier: orders ds ops; leaves global stores/loads in flight.
__device__ __forceinline__ void bar_lds()
{
    asm volatile("s_waitcnt lgkmcnt(0)" ::: "memory");
    __builtin_amdgcn_s_barrier();
}

// One recurrence step (parity-static buffers, ONE barrier per step).
//   AH_R: LDS tile holding h_T (read).       AH_P: tile to pack h_{T+1} into.
//   AX_N: tile holding x_{T+1} (read).       AX_W: tile to stage x_{T+2} into.
//   HB_N: h32 buffer for h_{T+1}.
// acc (a0..a3) enters holding the x-part of step T; leaves holding x-part T+1.
// Hazards: every tile written in step T is first read in step T+1; every read
// of step T precedes this wave's barrier arrival -> end-of-step bar suffices.
#define LSTM_STEP(T, AH_R, AH_P, AX_N, AX_W, HB_N)                            \
  {                                                                           \
    f16x8 xv0, xv1;                                                           \
    if ((T) < 1022) {     /* early-issue x_{T+2} (no h dependence) */         \
        xv0 = *(const f16x8*)(xb0 + (long)((T) + 2) * 512);                   \
        xv1 = *(const f16x8*)(xb1 + (long)((T) + 2) * 512);                   \
    }                                                                         \
    mfma_quad(AH_R, aoff, wfh, a0, a1, a2, a3);        /* += h_T @ Wh */      \
    _Pragma("unroll")                                                         \
    for (int j = 0; j < 4; ++j)                                               \
        ep[(rb * 4 + j) * 20 + c] = (a0[j] + a1[j]) + (a2[j] + a3[j]);        \
    if (lane < 32) {                                                          \
        float4 g4 = *(const float4*)(ep + er * 20 + eu * 4);   /* i,f,o,g */  \
        g4.x += b4.x; g4.y += b4.y; g4.z += b4.z; g4.w += b4.w;               \
        float iv = 1.f / (1.f + __expf(-g4.x));                               \
        float fv = 1.f / (1.f + __expf(-g4.y));                               \
        float ov = 1.f / (1.f + __expf(-g4.z));                               \
        float gv = 2.f / (1.f + __expf(-2.f * g4.w)) - 1.f;    /* tanh */     \
        float cn = fv * cst + iv * gv;                                        \
        cst = cn;                                                             \
        float th = 2.f / (1.f + __expf(-2.f * cn)) - 1.f;      /* tanh */     \
        float hval = ov * th;                                                 \
        if ((T) < 1023) {          /* critical store first (fire & forget) */ \
            union { f16 h; unsigned short s; } cv; cv.h = (f16)hval;          \
            unsigned hw = ((unsigned)((T) + 1) << 16) | (unsigned)cv.s;       \
            st_w32((HB_N) + er * 512 + ub + eu, hw);                          \
        }                                                                     \
        out[((long)(n0 + er) * 1024 + (T)) * 512 + ub + eu] = hval;           \
    }                                                                         \
    if ((T) < 1023) {                                                         \
        a0 = (f32x4){0.f,0.f,0.f,0.f}; a1 = (f32x4){0.f,0.f,0.f,0.f};         \
        a2 = (f32x4){0.f,0.f,0.f,0.f}; a3 = (f32x4){0.f,0.f,0.f,0.f};         \
        mfma_quad(AX_N, aoff, wfx, a0, a1, a2, a3);    /* x-part of T+1 */    \
        if ((T) < 1022) {          /* restage overlaps the poll window */     \
            *(f16x8*)((AX_W) + axo0) = xv0;                                   \
            *(f16x8*)((AX_W) + axo1) = xv1;                                   \
        }                                                                     \
        poll_stage(AH_P, HB_N, (unsigned)((T) + 1), tid);                     \
        bar_lds();                 /* the ONE barrier: all tiles published */  \
    }                                                                         \
  }

// Persistent recurrence kernel. 256 blocks x 256 threads (proven round-4 shape).
// group g = blk%8, wgl = blk/8 in [0,32). Group owns batch rows [8g,8g+8).
// Wave owns 4 hidden units -> 16 gate columns = one 16x16 MFMA N-tile, K=1024.
// x staged cooperatively through double-buffered LDS (8 VGPRs prefetch/thread);
// Ah double-buffered; ONE LDS barrier per step.
__global__ __launch_bounds__(256, 1) void lstm_kernel(
    const f16* __restrict__ x_h, const f16* __restrict__ Wcat,
    const float* __restrict__ b_p, u32* __restrict__ h32,
    float* __restrict__ out)
{
    __shared__ f16 Ah0[8 * AS];
    __shared__ f16 Ah1[8 * AS];
    __shared__ f16 Ax0[8 * AS];
    __shared__ f16 Ax1[8 * AS];
    __shared__ float epil[4 * 16 * 20];     // per-wave 16x20 gate transpose scratch

    const int blk  = blockIdx.x;
    const int g    = blk & 7;
    const int wgl  = blk >> 3;
    const int n0   = g * 8;
    const int tid  = threadIdx.x;
    const int wave = tid >> 6;
    const int lane = tid & 63;
    const int c    = lane & 15;             // tile column
    const int kg   = lane >> 4;             // k-group 0..3
    const int rb   = kg;
    const int ub   = wgl * 16 + wave * 4;   // first hidden unit of this wave
    const int q0   = ub * 4;                // first gate column

    // Weight B-fragments: x-part and h-part (compiler caches / L1-hot reload).
    f16x8 wfx[16], wfh[16];
    {
        const f16* wp = Wcat + (long)(q0 + c) * 1024 + kg * 8;
        #pragma unroll
        for (int kk = 0; kk < 16; ++kk) wfx[kk] = *(const f16x8*)(wp + kk * 32);
        #pragma unroll
        for (int kk = 0; kk < 16; ++kk) wfh[kk] = *(const f16x8*)(wp + 512 + kk * 32);
    }

    const int aoff = (lane & 7) * AS + kg * 8;
    float* ep = epil + wave * 320;
    const int er = lane >> 2;               // batch row 0..7 (epilogue)
    const int eu = lane & 3;                // unit-local 0..3
    const float4 b4 = *(const float4*)(b_p + q0 + eu * 4);   // per-cell biases
    float cst = 0.f;

    u32* hb0 = h32 + n0 * 512;
    u32* hb1 = h32 + 32768 + n0 * 512;

    // x staging addressing: thread covers rows pr0 and pr0+4, chunk pch
    const int pr0 = tid >> 6, pch = tid & 63;
    const f16* xb0 = x_h + ((long)(n0 + pr0)     * 1024) * 512 + pch * 8;
    const f16* xb1 = x_h + ((long)(n0 + pr0 + 4) * 1024) * 512 + pch * 8;
    const int axo0 = pr0       * AS + pch * 8;
    const int axo1 = (pr0 + 4) * AS + pch * 8;

    // ---- prologue: stage x_0 -> Ax0, x_1 -> Ax1, h_0 -> Ah0 ----
    *(f16x8*)(Ax0 + axo0) = *(const f16x8*)(xb0);
    *(f16x8*)(Ax0 + axo1) = *(const f16x8*)(xb1);
    *(f16x8*)(Ax1 + axo0) = *(const f16x8*)(xb0 + 512);
    *(f16x8*)(Ax1 + axo1) = *(const f16x8*)(xb1 + 512);
    poll_stage(Ah0, hb0, 0u, tid);          // prep wrote tag 0; succeeds first try
    bar_lds();

    f32x4 a0 = {0.f,0.f,0.f,0.f}, a1 = {0.f,0.f,0.f,0.f};
    f32x4 a2 = {0.f,0.f,0.f,0.f}, a3 = {0.f,0.f,0.f,0.f};
    mfma_quad(Ax0, aoff, wfx, a0, a1, a2, a3);   // x part, t=0
    bar_lds();   // Ax0 is overwritten at t=0; protect vs slower waves' reads

    for (int t = 0; t < 1024; t += 2) {
        LSTM_STEP(t,     Ah0, Ah1, Ax1, Ax0, hb1);  // h_t in Ah0, x_{t+1} in Ax1
        LSTM_STEP(t + 1, Ah1, Ah0, Ax0, Ax1, hb0);  // h_{t+1} in Ah1, x_{t+2} in Ax0
    }
}

extern "C" void kernel_launch(void* const* d_in, const int* in_sizes, int n_in,
                              void* d_out, int out_size, void* d_ws, size_t ws_size,
                              hipStream_t stream)
{
    const float* x  = (const float*)d_in[0];
    const float* h0 = (const float*)d_in[1];
    const float* Wx = (const float*)d_in[2];
    const float* Wh = (const float*)d_in[3];
    const float* b  = (const float*)d_in[4];
    float* out = (float*)d_out;

    char* ws = (char*)d_ws;
    f16*   x_h  = (f16*)(ws);
    f16*   Wcat = (f16*)(ws + OFF_WCAT);
    float* b_p  = (float*)(ws + OFF_BP);
    u32*   h32  = (u32*)(ws + OFF_H32);

    prep_kernel<<<16384, 256, 0, stream>>>(x, h0, Wx, Wh, b, x_h, Wcat, b_p, h32);
    lstm_kernel<<<256, 256, 0, stream>>>(x_h, Wcat, b_p, h32, out);
}